// Round 10
// baseline (195.526 us; speedup 1.0000x reference)
//
#include <hip/hip_runtime.h>
#include <hip/hip_bf16.h>

#define Bn 4096
#define Ln 512
#define Hn 32
#define MT 4  // m-tiles per block (grid = 128 bn x 8 mg)

using bf16x8 = __attribute__((ext_vector_type(8))) __bf16;
using f32x4  = __attribute__((ext_vector_type(4))) float;

#define GLOAD_LDS16(g, l)                                                          \
  __builtin_amdgcn_global_load_lds(                                                \
      (const __attribute__((address_space(1))) void*)(g),                          \
      (__attribute__((address_space(3))) void*)(l), 16, 0, 0)

__device__ __forceinline__ unsigned short f2bf(float x) {
  unsigned int u = __float_as_uint(x);
  unsigned int r = (u + 0x7FFFu + ((u >> 16) & 1u)) >> 16;
  return (unsigned short)r;
}

// Convert W1 [512*32*512] f32 -> bf16. Masked (upper-triangular) groups are
// ZERO-FILLED without reading W1. Reads ~half, writes all.
__global__ __launch_bounds__(256) void prep_w1_kernel(const float* __restrict__ W1,
                                                      unsigned short* __restrict__ W1b) {
  int idx = blockIdx.x * 256 + threadIdx.x;   // float4 group index
  const int n  = idx >> 7;                    // row in [0, 16384)
  const int c0 = (idx & 127) * 4;             // first col of group
  const int i  = n >> 5;                      // latent step of this row
  ushort4 o;
  if (c0 > i) {
    o.x = 0; o.y = 0; o.z = 0; o.w = 0;       // fully-masked group
  } else {
    const float4 f = reinterpret_cast<const float4*>(W1)[idx];
    o.x = f2bf(f.x); o.y = f2bf(f.y); o.z = f2bf(f.z); o.w = f2bf(f.w);
  }
  reinterpret_cast<ushort4*>(W1b)[idx] = o;
}

// Build V [4096,512] bf16
__global__ __launch_bounds__(256) void prep_v_kernel(const float* __restrict__ mu,
                                                     const float* __restrict__ log_var,
                                                     const float* __restrict__ eps0,
                                                     unsigned short* __restrict__ Vb) {
  int idx = blockIdx.x * 256 + threadIdx.x;
  int b = idx >> 9, j = idx & 511;
  float v;
  if (j == 0) {
    v = eps0[b] * expf(0.5f * log_var[(size_t)b * Ln]) + mu[(size_t)b * Ln];
  } else {
    v = mu[(size_t)b * Ln + j - 1];
  }
  Vb[idx] = f2bf(v);
}

// Fused: Hm = leaky_relu(V @ W1^T + b1); out = Hm @ W2^T + b2; sample.
// W1 (B) via double-buffered swizzled LDS; V (A) global->register with
// depth-1 ping-pong prefetch. ALL pipeline stages are MACRO-expanded with
// compile-time array indices (rounds 8/9 spilled: lambda array-refs broke
// SROA -> scratch; VGPR_Count 72/84 << live set). No launch_bounds cap.
// Counted vmcnt: body t issues A(t+1)(8 loads)+B(t+1)(4 gload_lds) then
// waits vmcnt(12) -> A(t)/B(t) drained, prefetch rides across barriers.
// Group-of-4 XCD striping (round 8: FETCH 35MB, WRITE 29MB).
__global__ __launch_bounds__(256) void gemm_fused_kernel(
    const unsigned short* __restrict__ Vb,   // [4096,512] bf16
    const unsigned short* __restrict__ W1b,  // [16384,512] bf16
    const float* __restrict__ b1,            // [512,32]
    const float* __restrict__ W2,            // [512,2,32]
    const float* __restrict__ b2,            // [512,2]
    const float* __restrict__ eps,           // [4096,512]
    float* __restrict__ out)                 // [3, 4096, 512]
{
  const int tid  = threadIdx.x;
  const int wid  = tid >> 6;
  const int lane = tid & 63;
  const int l15  = lane & 15;
  const int lq   = lane >> 4;

  // ---- group-of-4 XCD striping: group g = bn>>2 lives on XCD g&7.
  const int bid  = blockIdx.x;
  const int xcd  = bid & 7;
  const int s    = bid >> 3;              // 0..127
  const int g    = xcd + 8 * (3 - (s >> 5));
  const int bn   = g * 4 + ((s >> 3) & 3);
  const int mg   = s & 7;
  const int mb   = mg * (MT * 128);
  const int nb   = bn * 128;

  // triangular cutoff: block's i in [bn*4, bn*4+3] -> j <= bn*4+3
  const int ksteps = min(8, (bn + 16) >> 4);  // ceil((4bn+4)/64)

  __shared__ unsigned short Bs[2 * 128 * 64];  // 2 x 16 KiB (W1 only)

  // ---- B staging: chunk = 8 rows x 128 B; lane -> (row=lane>>3, slot=lane&7).
  // LDS linear slot (row, s) receives global element (row, s ^ row) [16B slots].
  const int rowc = lane >> 3;
  const int sswz = (lane & 7) ^ rowc;
  const unsigned short* gB = W1b + (size_t)(nb + wid * 32 + rowc) * Ln + sswz * 8;
  unsigned short* lB = Bs + wid * 2048;

#define STAGE_B(bufw, k0e)                                                     \
  do {                                                                         \
    _Pragma("unroll") for (int j_ = 0; j_ < 4; ++j_)                           \
        GLOAD_LDS16(gB + (k0e) + (size_t)j_ * 8 * Ln,                          \
                    lB + (bufw) * 8192 + j_ * 512);                            \
  } while (0)

  // ---- A direct-from-global (wave pair shares bytes via L1/L2)
  const unsigned short* gA = Vb + (size_t)(mb + (wid >> 1) * 64 + l15) * Ln;

#define LOAD_A(AN, mt_, k_)                                                    \
  do {                                                                         \
    const unsigned short* pa_ = gA + (size_t)(mt_) * (128 * Ln) + (k_) * 64;   \
    _Pragma("unroll") for (int ks2_ = 0; ks2_ < 2; ++ks2_)                     \
        _Pragma("unroll") for (int f_ = 0; f_ < 4; ++f_)                       \
            AN[ks2_][f_] = *reinterpret_cast<const bf16x8*>(                   \
                pa_ + (size_t)f_ * 16 * Ln + (ks2_ * 4 + lq) * 8);             \
  } while (0)

  // ---- B fragment reads: row = brow + f*16; linear slot = (ks2*4+lq) ^ (row&7)
  const int brow = (wid & 1) * 64 + l15;
  const int swz7 = l15 & 7;

  f32x4 acc[4][4];  // acc[fn][fm]: rows = n-side (i,h), cols = batch
#pragma unroll
  for (int fn = 0; fn < 4; ++fn)
#pragma unroll
    for (int fm = 0; fm < 4; ++fm) acc[fn][fm] = f32x4{0.f, 0.f, 0.f, 0.f};

#define COMPUTE(bufc, AC)                                                      \
  do {                                                                         \
    const int cofs_ = (bufc) * 8192;                                           \
    _Pragma("unroll") for (int ks2_ = 0; ks2_ < 2; ++ks2_) {                   \
      const int se_ = ((ks2_ * 4 + lq) ^ swz7) * 8;                            \
      bf16x8 bfr_[4];                                                          \
      _Pragma("unroll") for (int f_ = 0; f_ < 4; ++f_)                         \
          bfr_[f_] = *reinterpret_cast<const bf16x8*>(                         \
              Bs + cofs_ + (brow + f_ * 16) * 64 + se_);                       \
      _Pragma("unroll") for (int fn_ = 0; fn_ < 4; ++fn_)                      \
          _Pragma("unroll") for (int fm_ = 0; fm_ < 4; ++fm_)                  \
              acc[fn_][fm_] = __builtin_amdgcn_mfma_f32_16x16x32_bf16(         \
                  bfr_[fn_], AC[ks2_][fm_], acc[fn_][fm_], 0, 0, 0);           \
    }                                                                          \
  } while (0)

  float* mus = out;
  float* lvs = out + (size_t)Bn * Ln;
  float* smp = out + (size_t)2 * Bn * Ln;

#define EPILOGUE(mt_, bufc)                                                    \
  do {                                                                         \
    float* S_ = reinterpret_cast<float*>(Bs + (bufc) * 8192);                  \
    __builtin_amdgcn_s_barrier(); /* all waves done reading Bs[bufc] */        \
    const size_t o_ = (size_t)(mb + (mt_) * 128 + tid) * Ln + bn * 4;          \
    float4 ep_;                                                                \
    if (tid < 128) ep_ = *reinterpret_cast<const float4*>(eps + o_);           \
    const int wrow_ = (wid >> 1) * 64;                                         \
    _Pragma("unroll") for (int il_ = 0; il_ < 2; ++il_) {                      \
      const int i_   = bn * 4 + (wid & 1) * 2 + il_;                           \
      const int icl_ = (wid & 1) * 2 + il_;                                    \
      float4 b1q_[2], w20q_[2], w21q_[2];                                      \
      _Pragma("unroll") for (int q_ = 0; q_ < 2; ++q_) {                       \
        const int hb_ = q_ * 16 + lq * 4;                                      \
        b1q_[q_]  = *reinterpret_cast<const float4*>(b1 + i_ * Hn + hb_);      \
        w20q_[q_] = *reinterpret_cast<const float4*>(W2 + (i_ * 2 + 0) * Hn + hb_); \
        w21q_[q_] = *reinterpret_cast<const float4*>(W2 + (i_ * 2 + 1) * Hn + hb_); \
      }                                                                        \
      const float bias0_ = b2[i_ * 2 + 0];                                     \
      const float bias1_ = b2[i_ * 2 + 1];                                     \
      _Pragma("unroll") for (int fm_ = 0; fm_ < 4; ++fm_) {                    \
        float p0_ = 0.f, p1_ = 0.f;                                            \
        _Pragma("unroll") for (int q_ = 0; q_ < 2; ++q_) {                     \
          const f32x4& A_ = acc[il_ * 2 + q_][fm_];                            \
          const float* b1f_ = reinterpret_cast<const float*>(&b1q_[q_]);       \
          const float* w0f_ = reinterpret_cast<const float*>(&w20q_[q_]);      \
          const float* w1f_ = reinterpret_cast<const float*>(&w21q_[q_]);      \
          _Pragma("unroll") for (int r_ = 0; r_ < 4; ++r_) {                   \
            float x_  = A_[r_] + b1f_[r_];                                     \
            float hv_ = fmaxf(x_, 0.01f * x_); /* leaky_relu slope 0.01 */     \
            p0_ += hv_ * w0f_[r_];                                             \
            p1_ += hv_ * w1f_[r_];                                             \
          }                                                                    \
        }                                                                      \
        p0_ += __shfl_xor(p0_, 16);                                            \
        p0_ += __shfl_xor(p0_, 32);                                            \
        p1_ += __shfl_xor(p1_, 16);                                            \
        p1_ += __shfl_xor(p1_, 32);                                            \
        if (lq == 0) {                                                         \
          const int r_ = wrow_ + fm_ * 16 + l15;                               \
          S_[icl_ * 128 + r_]       = p0_ + bias0_;                            \
          S_[512 + icl_ * 128 + r_] = p1_ + bias1_;                            \
        }                                                                      \
      }                                                                        \
    }                                                                          \
    asm volatile("s_waitcnt lgkmcnt(0)" ::: "memory");                         \
    __builtin_amdgcn_s_barrier();                                              \
    if (tid < 128) {                                                           \
      const int r_ = tid;                                                      \
      float4 muv_, lvv_;                                                       \
      muv_.x = S_[r_];       muv_.y = S_[128 + r_];                            \
      muv_.z = S_[256 + r_]; muv_.w = S_[384 + r_];                            \
      lvv_.x = S_[512 + r_]; lvv_.y = S_[640 + r_];                            \
      lvv_.z = S_[768 + r_]; lvv_.w = S_[896 + r_];                            \
      float4 sm_;                                                              \
      sm_.x = ep_.x * __builtin_exp2f(lvv_.x * 0.7213475204444817f) + muv_.x;  \
      sm_.y = ep_.y * __builtin_exp2f(lvv_.y * 0.7213475204444817f) + muv_.y;  \
      sm_.z = ep_.z * __builtin_exp2f(lvv_.z * 0.7213475204444817f) + muv_.z;  \
      sm_.w = ep_.w * __builtin_exp2f(lvv_.w * 0.7213475204444817f) + muv_.w;  \
      *reinterpret_cast<float4*>(mus + o_) = muv_;                             \
      *reinterpret_cast<float4*>(lvs + o_) = lvv_;                             \
      *reinterpret_cast<float4*>(smp + o_) = sm_;                              \
    }                                                                          \
    _Pragma("unroll") for (int fn_ = 0; fn_ < 4; ++fn_)                        \
        _Pragma("unroll") for (int fm_ = 0; fm_ < 4; ++fm_)                    \
            acc[fn_][fm_] = f32x4{0.f, 0.f, 0.f, 0.f};                         \
  } while (0)

#define BODY(AC, AN)                                                           \
  {                                                                            \
    int kn_ = k + 1, mtn_ = mt;                                                \
    if (kn_ == ksteps) { kn_ = 0; ++mtn_; }                                    \
    if (mtn_ < MT) {                                                           \
      LOAD_A(AN, mtn_, kn_);                           /* 8 newest */          \
      STAGE_B(buf ^ 1, kn_ * 64);                      /* +4 newest */         \
      asm volatile("s_waitcnt vmcnt(12)" ::: "memory"); /* drain A(t)+B(t) */  \
    } else {                                                                   \
      asm volatile("s_waitcnt vmcnt(0)" ::: "memory");  /* last: full drain */ \
    }                                                                          \
    __builtin_amdgcn_s_barrier();                                              \
    __builtin_amdgcn_sched_barrier(0);                                         \
    COMPUTE(buf, AC);                                                          \
    if (k == ksteps - 1) EPILOGUE(mt, buf);                                    \
    __builtin_amdgcn_s_barrier();                                              \
    buf ^= 1; k = kn_; mt = mtn_;                                              \
  }

  // ================= pipelined main loop =================
  bf16x8 aP[2][4], aQ[2][4];  // A register ping-pong (depth-1 prefetch)
  int mt = 0, k = 0, buf = 0;

  LOAD_A(aP, 0, 0);
  STAGE_B(0, 0);

  const int T = MT * ksteps;  // always even (MT = 4)
  for (int it = 0; it < T; it += 2) {
    BODY(aP, aQ);
    BODY(aQ, aP);
  }
}

extern "C" void kernel_launch(void* const* d_in, const int* in_sizes, int n_in,
                              void* d_out, int out_size, void* d_ws, size_t ws_size,
                              hipStream_t stream) {
  const float* mu      = (const float*)d_in[0];
  const float* log_var = (const float*)d_in[1];
  const float* eps0    = (const float*)d_in[2];
  const float* eps     = (const float*)d_in[3];
  const float* W1      = (const float*)d_in[4];
  const float* b1      = (const float*)d_in[5];
  const float* W2      = (const float*)d_in[6];
  const float* b2      = (const float*)d_in[7];
  float* out = (float*)d_out;

  unsigned short* Vb  = (unsigned short*)d_ws;                                  // 4 MiB
  unsigned short* W1b = (unsigned short*)((char*)d_ws + (size_t)Bn * Ln * 2);   // 16 MiB

  prep_v_kernel<<<(Bn * Ln) / 256, 256, 0, stream>>>(mu, log_var, eps0, Vb);
  prep_w1_kernel<<<(Ln * Hn * Ln) / 4 / 256, 256, 0, stream>>>(W1, W1b);
  gemm_fused_kernel<<<128 * (32 / MT), 256, 0, stream>>>(
      Vb, W1b, b1, W2, b2, eps, out);
}

// Round 11
// 95.397 us; speedup vs baseline: 2.0496x; 2.0496x over previous
//
#include <hip/hip_runtime.h>
#include <hip/hip_bf16.h>

#define Bn 4096
#define Ln 512
#define Hn 32
#define MT 4  // m-tiles per block (grid = 128 bn x 8 mg)

using bf16x8 = __attribute__((ext_vector_type(8))) __bf16;
using f32x4  = __attribute__((ext_vector_type(4))) float;

#define GLOAD_LDS16(g, l)                                                          \
  __builtin_amdgcn_global_load_lds(                                                \
      (const __attribute__((address_space(1))) void*)(g),                          \
      (__attribute__((address_space(3))) void*)(l), 16, 0, 0)

__device__ __forceinline__ unsigned short f2bf(float x) {
  unsigned int u = __float_as_uint(x);
  unsigned int r = (u + 0x7FFFu + ((u >> 16) & 1u)) >> 16;
  return (unsigned short)r;
}

// Convert W1 [512*32*512] f32 -> bf16. Masked (upper-triangular) groups are
// ZERO-FILLED without reading W1. Reads ~half, writes all.
__global__ __launch_bounds__(256) void prep_w1_kernel(const float* __restrict__ W1,
                                                      unsigned short* __restrict__ W1b) {
  int idx = blockIdx.x * 256 + threadIdx.x;   // float4 group index
  const int n  = idx >> 7;                    // row in [0, 16384)
  const int c0 = (idx & 127) * 4;             // first col of group
  const int i  = n >> 5;                      // latent step of this row
  ushort4 o;
  if (c0 > i) {
    o.x = 0; o.y = 0; o.z = 0; o.w = 0;       // fully-masked group
  } else {
    const float4 f = reinterpret_cast<const float4*>(W1)[idx];
    o.x = f2bf(f.x); o.y = f2bf(f.y); o.z = f2bf(f.z); o.w = f2bf(f.w);
  }
  reinterpret_cast<ushort4*>(W1b)[idx] = o;
}

// Build V [4096,512] bf16
__global__ __launch_bounds__(256) void prep_v_kernel(const float* __restrict__ mu,
                                                     const float* __restrict__ log_var,
                                                     const float* __restrict__ eps0,
                                                     unsigned short* __restrict__ Vb) {
  int idx = blockIdx.x * 256 + threadIdx.x;
  int b = idx >> 9, j = idx & 511;
  float v;
  if (j == 0) {
    v = eps0[b] * expf(0.5f * log_var[(size_t)b * Ln]) + mu[(size_t)b * Ln];
  } else {
    v = mu[(size_t)b * Ln + j - 1];
  }
  Vb[idx] = f2bf(v);
}

// Fused: Hm = leaky_relu(V @ W1^T + b1); out = Hm @ W2^T + b2; sample.
// ROUND-6 staging structure (best measured: both operands global_load_lds,
// BK=64, double-buffered, counted vmcnt(8), 2 barriers/iter) +
//  - group-of-4 XCD striping (round 8: FETCH 35MB, write-merge preserved)
//  - BARRIER-FREE epilogue: eps/b1/W2/b2 issued as a counted 17-op VMEM
//    window BEFORE the prefetch STAGE (so they are OLDER than it); their
//    use-waits are then vmcnt(8) and never drain the pipeline. Outputs
//    stored scattered fire-and-forget (no LDS transpose, no extra barriers).
__global__ __launch_bounds__(256) void gemm_fused_kernel(
    const unsigned short* __restrict__ Vb,   // [4096,512] bf16
    const unsigned short* __restrict__ W1b,  // [16384,512] bf16
    const float* __restrict__ b1,            // [512,32]
    const float* __restrict__ W2,            // [512,2,32]
    const float* __restrict__ b2,            // [512,2]
    const float* __restrict__ eps,           // [4096,512]
    float* __restrict__ out)                 // [3, 4096, 512]
{
  const int tid  = threadIdx.x;
  const int wid  = tid >> 6;
  const int lane = tid & 63;
  const int l15  = lane & 15;
  const int lq   = lane >> 4;

  // ---- group-of-4 XCD striping: group g = bn>>2 lives on XCD g&7 (heavy first)
  const int bid  = blockIdx.x;
  const int xcd  = bid & 7;
  const int s    = bid >> 3;              // 0..127
  const int g    = xcd + 8 * (3 - (s >> 5));
  const int bn   = g * 4 + ((s >> 3) & 3);
  const int mg   = s & 7;
  const int mb   = mg * (MT * 128);
  const int nb   = bn * 128;

  // triangular cutoff: block's i in [bn*4, bn*4+3] -> j <= bn*4+3
  const int ksteps = min(8, (bn + 16) >> 4);  // ceil((4bn+4)/64)

  __shared__ unsigned short As[2 * 128 * 64];  // 2 x 16 KiB
  __shared__ unsigned short Bs[2 * 128 * 64];  // 2 x 16 KiB

  // ---- staging: chunk = 8 rows x 128 B; lane -> (row=lane>>3, slot=lane&7).
  // LDS linear slot (row, s) receives global element (row, s ^ row) [16B slots].
  const int rowc = lane >> 3;
  const int sswz = (lane & 7) ^ rowc;
  const unsigned short* gA = Vb  + (size_t)(mb + wid * 32 + rowc) * Ln + sswz * 8;
  const unsigned short* gB = W1b + (size_t)(nb + wid * 32 + rowc) * Ln + sswz * 8;
  unsigned short* lA = As + wid * 2048;
  unsigned short* lB = Bs + wid * 2048;

  auto STAGE = [&](int bufw, int mt_, int k0e) {  // 8 VMEM ops
    const int    lofs = bufw * 8192;
    const size_t ga   = (size_t)mt_ * (128 * Ln) + k0e;
#pragma unroll
    for (int j = 0; j < 4; ++j) {
      GLOAD_LDS16(gA + ga + (size_t)j * 8 * Ln, lA + lofs + j * 512);
      GLOAD_LDS16(gB + k0e + (size_t)j * 8 * Ln, lB + lofs + j * 512);
    }
  };

  // ---- fragment reads: row = base + l15 (+f*16); linear slot = (ks2*4+lq) ^ (row&7)
  const int arow = (wid >> 1) * 64 + l15;
  const int brow = (wid & 1) * 64 + l15;
  const int swz7 = l15 & 7;

  f32x4 acc[4][4];  // acc[fn][fm]: rows = n-side (i,h), cols = batch
#pragma unroll
  for (int fn = 0; fn < 4; ++fn)
#pragma unroll
    for (int fm = 0; fm < 4; ++fm) acc[fn][fm] = f32x4{0.f, 0.f, 0.f, 0.f};

  auto COMPUTE = [&](int bufc) {
    const int cofs = bufc * 8192;
#pragma unroll
    for (int ks2 = 0; ks2 < 2; ++ks2) {
      const int se = ((ks2 * 4 + lq) ^ swz7) * 8;
      bf16x8 a[4], b[4];
#pragma unroll
      for (int f = 0; f < 4; ++f) {
        a[f] = *reinterpret_cast<const bf16x8*>(As + cofs + (arow + f * 16) * 64 + se);
        b[f] = *reinterpret_cast<const bf16x8*>(Bs + cofs + (brow + f * 16) * 64 + se);
      }
#pragma unroll
      for (int fn = 0; fn < 4; ++fn)
#pragma unroll
        for (int fm = 0; fm < 4; ++fm)
          acc[fn][fm] = __builtin_amdgcn_mfma_f32_16x16x32_bf16(b[fn], a[ks2 ? fm : fm],
                                                                acc[fn][fm], 0, 0, 0),
          (void)0;
    }
  };
  // NOTE: a[] is re-read per ks2 inside the loop above; the ternary is a no-op
  // kept only to avoid unused-variable pruning confusion. (a[f] depends on se.)

  float* mus = out;
  float* lvs = out + (size_t)Bn * Ln;
  float* smp = out + (size_t)2 * Bn * Ln;

  int buf = 0;
  STAGE(0, 0, 0);

  for (int mt = 0; mt < MT; ++mt) {
    for (int k = 0; k < ksteps; ++k) {
      int kn = k + 1, mtn = mt;
      if (kn == ksteps) { kn = 0; ++mtn; }
      const bool epi  = (k == ksteps - 1);
      const bool more = (mtn < MT);

      // ---- epilogue pre-window: 17 VMEM ops, issued BEFORE the prefetch so
      // they are OLDER than it (use-waits become vmcnt(8), prefetch rides on).
      float2 ep2[4];
      float4 b1q[2][2], w20q[2][2], w21q[2][2], b2q;
      if (epi) {
        int zero;  // address laundering: blocks LICM / SMEM promotion
        asm volatile("v_mov_b32 %0, 0" : "=v"(zero));
        const int    wrow = (wid >> 1) * 64;
        const size_t er   = (size_t)(mb + mt * 128 + wrow + l15);
        const int    ec   = bn * 4 + (wid & 1) * 2;
#pragma unroll
        for (int fm = 0; fm < 4; ++fm)  // 4 x dwordx2
          ep2[fm] = *reinterpret_cast<const float2*>(eps + (er + fm * 16) * Ln + ec + zero);
#pragma unroll
        for (int il = 0; il < 2; ++il) {
          const int i = bn * 4 + (wid & 1) * 2 + il;
#pragma unroll
          for (int q = 0; q < 2; ++q) {  // 12 x dwordx4
            const int hb = q * 16 + lq * 4 + zero;
            b1q[il][q]  = *reinterpret_cast<const float4*>(b1 + i * Hn + hb);
            w20q[il][q] = *reinterpret_cast<const float4*>(W2 + (i * 2 + 0) * Hn + hb);
            w21q[il][q] = *reinterpret_cast<const float4*>(W2 + (i * 2 + 1) * Hn + hb);
          }
        }
        // 1 x dwordx4 covering b2[i0*2 .. i0*2+3] (i0 even -> 16B aligned)
        b2q = *reinterpret_cast<const float4*>(b2 + (bn * 4 + (wid & 1) * 2) * 2 + zero);
        __builtin_amdgcn_sched_barrier(0);  // pin pre-window above STAGE
      }

      if (more) {
        STAGE(buf ^ 1, mtn, kn * 64);  // 8 newest
        if (epi) asm volatile("s_waitcnt vmcnt(25)" ::: "memory");  // drain s(t), keep 17+8
        else     asm volatile("s_waitcnt vmcnt(8)"  ::: "memory");  // drain s(t), keep 8
      } else {
        asm volatile("s_waitcnt vmcnt(17)" ::: "memory");           // drain s(t), keep 17
      }
      __builtin_amdgcn_s_barrier();
      __builtin_amdgcn_sched_barrier(0);  // pin ds_reads below the barrier
      COMPUTE(buf);

      if (epi) {
        // ---- barrier-free epilogue: registers only, scattered f-a-f stores
        const int wrow = (wid >> 1) * 64;
#pragma unroll
        for (int il = 0; il < 2; ++il) {
          const int   icl   = (wid & 1) * 2 + il;
          const float bias0 = (il == 0) ? b2q.x : b2q.z;
          const float bias1 = (il == 0) ? b2q.y : b2q.w;
#pragma unroll
          for (int fm = 0; fm < 4; ++fm) {
            float p0 = 0.f, p1 = 0.f;
#pragma unroll
            for (int q = 0; q < 2; ++q) {
              const f32x4& A = acc[il * 2 + q][fm];
              const float* b1f = reinterpret_cast<const float*>(&b1q[il][q]);
              const float* w0f = reinterpret_cast<const float*>(&w20q[il][q]);
              const float* w1f = reinterpret_cast<const float*>(&w21q[il][q]);
#pragma unroll
              for (int r = 0; r < 4; ++r) {
                float x  = A[r] + b1f[r];
                float hv = fmaxf(x, 0.01f * x);  // leaky_relu (slope 0.01)
                p0 += hv * w0f[r];
                p1 += hv * w1f[r];
              }
            }
            p0 += __shfl_xor(p0, 16);
            p0 += __shfl_xor(p0, 32);
            p1 += __shfl_xor(p1, 16);
            p1 += __shfl_xor(p1, 32);
            if (lq == 0) {
              const size_t o = (size_t)(mb + mt * 128 + wrow + fm * 16 + l15) * Ln
                               + bn * 4 + icl;
              const float mu_o = p0 + bias0;
              const float lv_o = p1 + bias1;
              const float ep   = (il == 0) ? ep2[fm].x : ep2[fm].y;
              mus[o] = mu_o;
              lvs[o] = lv_o;
              smp[o] = ep * __builtin_exp2f(lv_o * 0.7213475204444817f) + mu_o;
            }
          }
        }
        // reset accumulators for the next m-tile
#pragma unroll
        for (int fn = 0; fn < 4; ++fn)
#pragma unroll
          for (int fm = 0; fm < 4; ++fm) acc[fn][fm] = f32x4{0.f, 0.f, 0.f, 0.f};
      }
      __builtin_amdgcn_s_barrier();  // buffer free for next STAGE
      buf ^= 1;
    }
  }
}

extern "C" void kernel_launch(void* const* d_in, const int* in_sizes, int n_in,
                              void* d_out, int out_size, void* d_ws, size_t ws_size,
                              hipStream_t stream) {
  const float* mu      = (const float*)d_in[0];
  const float* log_var = (const float*)d_in[1];
  const float* eps0    = (const float*)d_in[2];
  const float* eps     = (const float*)d_in[3];
  const float* W1      = (const float*)d_in[4];
  const float* b1      = (const float*)d_in[5];
  const float* W2      = (const float*)d_in[6];
  const float* b2      = (const float*)d_in[7];
  float* out = (float*)d_out;

  unsigned short* Vb  = (unsigned short*)d_ws;                                  // 4 MiB
  unsigned short* W1b = (unsigned short*)((char*)d_ws + (size_t)Bn * Ln * 2);   // 16 MiB

  prep_v_kernel<<<(Bn * Ln) / 256, 256, 0, stream>>>(mu, log_var, eps0, Vb);
  prep_w1_kernel<<<(Ln * Hn * Ln) / 4 / 256, 256, 0, stream>>>(W1, W1b);
  gemm_fused_kernel<<<128 * (32 / MT), 256, 0, stream>>>(
      Vb, W1b, b1, W2, b2, eps, out);
}

// Round 12
// 91.651 us; speedup vs baseline: 2.1334x; 1.0409x over previous
//
#include <hip/hip_runtime.h>
#include <hip/hip_bf16.h>

#define Bn 4096
#define Ln 512
#define Hn 32
#define MT 4  // m-tiles per block (grid = 128 bn x 8 mg)

using bf16x8 = __attribute__((ext_vector_type(8))) __bf16;
using f32x4  = __attribute__((ext_vector_type(4))) float;

#define GLOAD_LDS16(g, l)                                                          \
  __builtin_amdgcn_global_load_lds(                                                \
      (const __attribute__((address_space(1))) void*)(g),                          \
      (__attribute__((address_space(3))) void*)(l), 16, 0, 0)

__device__ __forceinline__ unsigned short f2bf(float x) {
  unsigned int u = __float_as_uint(x);
  unsigned int r = (u + 0x7FFFu + ((u >> 16) & 1u)) >> 16;
  return (unsigned short)r;
}

// Convert W1 [512*32*512] f32 -> bf16. Masked (upper-triangular) groups are
// ZERO-FILLED without reading W1. Reads ~half, writes all.
__global__ __launch_bounds__(256) void prep_w1_kernel(const float* __restrict__ W1,
                                                      unsigned short* __restrict__ W1b) {
  int idx = blockIdx.x * 256 + threadIdx.x;   // float4 group index
  const int n  = idx >> 7;                    // row in [0, 16384)
  const int c0 = (idx & 127) * 4;             // first col of group
  const int i  = n >> 5;                      // latent step of this row
  ushort4 o;
  if (c0 > i) {
    o.x = 0; o.y = 0; o.z = 0; o.w = 0;       // fully-masked group
  } else {
    const float4 f = reinterpret_cast<const float4*>(W1)[idx];
    o.x = f2bf(f.x); o.y = f2bf(f.y); o.z = f2bf(f.z); o.w = f2bf(f.w);
  }
  reinterpret_cast<ushort4*>(W1b)[idx] = o;
}

// Build V [4096,512] bf16
__global__ __launch_bounds__(256) void prep_v_kernel(const float* __restrict__ mu,
                                                     const float* __restrict__ log_var,
                                                     const float* __restrict__ eps0,
                                                     unsigned short* __restrict__ Vb) {
  int idx = blockIdx.x * 256 + threadIdx.x;
  int b = idx >> 9, j = idx & 511;
  float v;
  if (j == 0) {
    v = eps0[b] * expf(0.5f * log_var[(size_t)b * Ln]) + mu[(size_t)b * Ln];
  } else {
    v = mu[(size_t)b * Ln + j - 1];
  }
  Vb[idx] = f2bf(v);
}

// Fused: Hm = leaky_relu(V @ W1^T + b1); out = Hm @ W2^T + b2; sample.
// ROUND-6 structure (best: 77.5us) with ONE variable changed: BK 64->32.
// LDS 64KB -> 32KB => ~5 blocks/CU resident (was 2): the counters showed a
// latency-bound kernel (no pipe >35%), so TLP is the missing resource.
// Double-buffered counted-vmcnt(4) pipeline over flattened (m-tile, k) loop;
// group-of-4 XCD striping (FETCH ~36MB validated R8/R11); LDS-transposed
// float4 epilogue (clean WRITE ~25-29MB validated R6/R8).
__global__ __launch_bounds__(256) void gemm_fused_kernel(
    const unsigned short* __restrict__ Vb,   // [4096,512] bf16
    const unsigned short* __restrict__ W1b,  // [16384,512] bf16
    const float* __restrict__ b1,            // [512,32]
    const float* __restrict__ W2,            // [512,2,32]
    const float* __restrict__ b2,            // [512,2]
    const float* __restrict__ eps,           // [4096,512]
    float* __restrict__ out)                 // [3, 4096, 512]
{
  const int tid  = threadIdx.x;
  const int wid  = tid >> 6;
  const int lane = tid & 63;
  const int l15  = lane & 15;
  const int lq   = lane >> 4;

  // ---- group-of-4 XCD striping: group g = bn>>2 lives on XCD g&7 (heavy first)
  const int bid  = blockIdx.x;
  const int xcd  = bid & 7;
  const int s    = bid >> 3;              // 0..127
  const int g    = xcd + 8 * (3 - (s >> 5));
  const int bn   = g * 4 + ((s >> 3) & 3);
  const int mg   = s & 7;
  const int mb   = mg * (MT * 128);
  const int nb   = bn * 128;

  // triangular cutoff: block's i in [bn*4, bn*4+3] -> j <= bn*4+3
  const int ksteps = min(16, (4 * bn + 4 + 31) >> 5);

  __shared__ unsigned short As[2 * 128 * 32];  // 2 x 8 KiB
  __shared__ unsigned short Bs[2 * 128 * 32];  // 2 x 8 KiB

  // ---- staging: chunk = 16 rows x 64 B = 1 KiB; lane -> (row=lane>>2, slot=lane&3).
  // LDS linear slot (row, s) receives global slot s ^ ((row>>1)&3) [16B slots]
  // => pre-swizzled SOURCE address (round-1/2-validated swizzle pair).
  const int rowc = lane >> 2;
  const int sswz = (lane & 3) ^ ((lane >> 3) & 3);
  const unsigned short* gA = Vb  + (size_t)(mb + wid * 32 + rowc) * Ln + sswz * 8;
  const unsigned short* gB = W1b + (size_t)(nb + wid * 32 + rowc) * Ln + sswz * 8;
  unsigned short* lA = As + wid * 1024;  // 32 rows x 32 elems per wave
  unsigned short* lB = Bs + wid * 1024;

  auto STAGE = [&](int bufw, int mt_, int k0e) {  // 4 VMEM ops per wave
    const int    lofs = bufw * 4096;
    const size_t ga   = (size_t)mt_ * (128 * Ln) + k0e;
    GLOAD_LDS16(gA + ga, lA + lofs);
    GLOAD_LDS16(gA + ga + (size_t)16 * Ln, lA + lofs + 512);
    GLOAD_LDS16(gB + k0e, lB + lofs);
    GLOAD_LDS16(gB + k0e + (size_t)16 * Ln, lB + lofs + 512);
  };

  // ---- fragment reads: row = base + l15 (+f*16); k-slot lq; linear slot =
  // lq ^ ((row>>1)&3); (row>>1)&3 == (l15>>1)&3 for all f (16-row stride).
  const int arow = (wid >> 1) * 64 + l15;
  const int brow = (wid & 1) * 64 + l15;
  const int se   = (lq ^ ((l15 >> 1) & 3)) * 8;  // ushort offset within row

  f32x4 acc[4][4];  // acc[fn][fm]: rows = n-side (i,h), cols = batch
#pragma unroll
  for (int fn = 0; fn < 4; ++fn)
#pragma unroll
    for (int fm = 0; fm < 4; ++fm) acc[fn][fm] = f32x4{0.f, 0.f, 0.f, 0.f};

  auto COMPUTE = [&](int bufc) {
    const int cofs = bufc * 4096;
    bf16x8 a[4], b[4];
#pragma unroll
    for (int f = 0; f < 4; ++f) {
      a[f] = *reinterpret_cast<const bf16x8*>(As + cofs + (arow + f * 16) * 32 + se);
      b[f] = *reinterpret_cast<const bf16x8*>(Bs + cofs + (brow + f * 16) * 32 + se);
    }
#pragma unroll
    for (int fn = 0; fn < 4; ++fn)
#pragma unroll
      for (int fm = 0; fm < 4; ++fm)
        acc[fn][fm] = __builtin_amdgcn_mfma_f32_16x16x32_bf16(b[fn], a[fm],
                                                              acc[fn][fm], 0, 0, 0);
  };

  float* mus = out;
  float* lvs = out + (size_t)Bn * Ln;
  float* smp = out + (size_t)2 * Bn * Ln;

  int buf = 0;
  STAGE(0, 0, 0);

  for (int mt = 0; mt < MT; ++mt) {
    for (int k = 0; k < ksteps; ++k) {
      int kn = k + 1, mtn = mt;
      if (kn == ksteps) { kn = 0; ++mtn; }
      if (mtn < MT) {
        STAGE(buf ^ 1, mtn, kn * 32);                    // 4 newest VMEM ops
        asm volatile("s_waitcnt vmcnt(4)" ::: "memory"); // wait current tile only
      } else {
        asm volatile("s_waitcnt vmcnt(0)" ::: "memory"); // last iter: full drain
      }
      __builtin_amdgcn_s_barrier();
      __builtin_amdgcn_sched_barrier(0);  // pin ds_reads below the barrier
      COMPUTE(buf);

      if (k == ksteps - 1) {
        // ======== per-m-tile epilogue (block-uniform branch) ========
        // Scratch: just-consumed B buffer (prefetch writes buf^1; disjoint).
        // Layout: S[2][4][128] f32 = 4 KiB ({mu,lv} x i_local x row).
        float* S = reinterpret_cast<float*>(Bs + buf * 4096);
        __builtin_amdgcn_s_barrier();  // all waves done reading Bs[buf]

        const int wrow = (wid >> 1) * 64;
#pragma unroll
        for (int il = 0; il < 2; ++il) {
          const int i   = bn * 4 + (wid & 1) * 2 + il;
          const int icl = (wid & 1) * 2 + il;
          float4 b1q[2], w20q[2], w21q[2];
#pragma unroll
          for (int q = 0; q < 2; ++q) {
            const int hb = q * 16 + lq * 4;
            b1q[q]  = *reinterpret_cast<const float4*>(b1 + i * Hn + hb);
            w20q[q] = *reinterpret_cast<const float4*>(W2 + (i * 2 + 0) * Hn + hb);
            w21q[q] = *reinterpret_cast<const float4*>(W2 + (i * 2 + 1) * Hn + hb);
          }
          const float bias0 = b2[i * 2 + 0];
          const float bias1 = b2[i * 2 + 1];
#pragma unroll
          for (int fm = 0; fm < 4; ++fm) {
            float p0 = 0.f, p1 = 0.f;
#pragma unroll
            for (int q = 0; q < 2; ++q) {
              const f32x4& A = acc[il * 2 + q][fm];
              const float* b1f = reinterpret_cast<const float*>(&b1q[q]);
              const float* w0f = reinterpret_cast<const float*>(&w20q[q]);
              const float* w1f = reinterpret_cast<const float*>(&w21q[q]);
#pragma unroll
              for (int r = 0; r < 4; ++r) {
                float x  = A[r] + b1f[r];
                float hv = fmaxf(x, 0.01f * x);  // leaky_relu (slope 0.01)
                p0 += hv * w0f[r];
                p1 += hv * w1f[r];
              }
            }
            p0 += __shfl_xor(p0, 16);
            p0 += __shfl_xor(p0, 32);
            p1 += __shfl_xor(p1, 16);
            p1 += __shfl_xor(p1, 32);
            if (lq == 0) {
              const int r = wrow + fm * 16 + l15;
              S[icl * 128 + r]       = p0 + bias0;
              S[512 + icl * 128 + r] = p1 + bias1;
            }
          }
        }
        asm volatile("s_waitcnt lgkmcnt(0)" ::: "memory");  // ds_writes visible
        __builtin_amdgcn_s_barrier();

        if (tid < 128) {  // wave-uniform: waves 0,1 active
          const int    r = tid;
          const size_t o = (size_t)(mb + mt * 128 + r) * Ln + bn * 4;
          float4 muv, lvv;
          muv.x = S[r];       muv.y = S[128 + r]; muv.z = S[256 + r]; muv.w = S[384 + r];
          lvv.x = S[512 + r]; lvv.y = S[640 + r]; lvv.z = S[768 + r]; lvv.w = S[896 + r];
          const float4 ep = *reinterpret_cast<const float4*>(eps + o);
          float4 sm;
          sm.x = ep.x * __builtin_exp2f(lvv.x * 0.7213475204444817f) + muv.x;
          sm.y = ep.y * __builtin_exp2f(lvv.y * 0.7213475204444817f) + muv.y;
          sm.z = ep.z * __builtin_exp2f(lvv.z * 0.7213475204444817f) + muv.z;
          sm.w = ep.w * __builtin_exp2f(lvv.w * 0.7213475204444817f) + muv.w;
          *reinterpret_cast<float4*>(mus + o) = muv;
          *reinterpret_cast<float4*>(lvs + o) = lvv;
          *reinterpret_cast<float4*>(smp + o) = sm;
        }
        // reset accumulators for the next m-tile
#pragma unroll
        for (int fn = 0; fn < 4; ++fn)
#pragma unroll
          for (int fm = 0; fm < 4; ++fm) acc[fn][fm] = f32x4{0.f, 0.f, 0.f, 0.f};
      }
      __builtin_amdgcn_s_barrier();  // buffer free for next STAGE
      buf ^= 1;
    }
  }
}

extern "C" void kernel_launch(void* const* d_in, const int* in_sizes, int n_in,
                              void* d_out, int out_size, void* d_ws, size_t ws_size,
                              hipStream_t stream) {
  const float* mu      = (const float*)d_in[0];
  const float* log_var = (const float*)d_in[1];
  const float* eps0    = (const float*)d_in[2];
  const float* eps     = (const float*)d_in[3];
  const float* W1      = (const float*)d_in[4];
  const float* b1      = (const float*)d_in[5];
  const float* W2      = (const float*)d_in[6];
  const float* b2      = (const float*)d_in[7];
  float* out = (float*)d_out;

  unsigned short* Vb  = (unsigned short*)d_ws;                                  // 4 MiB
  unsigned short* W1b = (unsigned short*)((char*)d_ws + (size_t)Bn * Ln * 2);   // 16 MiB

  prep_v_kernel<<<(Bn * Ln) / 256, 256, 0, stream>>>(mu, log_var, eps0, Vb);
  prep_w1_kernel<<<(Ln * Hn * Ln) / 4 / 256, 256, 0, stream>>>(W1, W1b);
  gemm_fused_kernel<<<128 * (32 / MT), 256, 0, stream>>>(
      Vb, W1b, b1, W2, b2, eps, out);
}

// Round 13
// 81.929 us; speedup vs baseline: 2.3865x; 1.1187x over previous
//
#include <hip/hip_runtime.h>
#include <hip/hip_bf16.h>

#define Bn 4096
#define Ln 512
#define Hn 32
#define MT 4  // m-tiles per block (grid = 128 bn x 8 mg)

using bf16x8 = __attribute__((ext_vector_type(8))) __bf16;
using f32x4  = __attribute__((ext_vector_type(4))) float;

#define GLOAD_LDS16(g, l)                                                          \
  __builtin_amdgcn_global_load_lds(                                                \
      (const __attribute__((address_space(1))) void*)(g),                          \
      (__attribute__((address_space(3))) void*)(l), 16, 0, 0)

__device__ __forceinline__ unsigned short f2bf(float x) {
  unsigned int u = __float_as_uint(x);
  unsigned int r = (u + 0x7FFFu + ((u >> 16) & 1u)) >> 16;
  return (unsigned short)r;
}

// Convert W1 [512*32*512] f32 -> bf16. Masked (upper-triangular) groups are
// ZERO-FILLED without reading W1. Reads ~half, writes all.
__global__ __launch_bounds__(256) void prep_w1_kernel(const float* __restrict__ W1,
                                                      unsigned short* __restrict__ W1b) {
  int idx = blockIdx.x * 256 + threadIdx.x;   // float4 group index
  const int n  = idx >> 7;                    // row in [0, 16384)
  const int c0 = (idx & 127) * 4;             // first col of group
  const int i  = n >> 5;                      // latent step of this row
  ushort4 o;
  if (c0 > i) {
    o.x = 0; o.y = 0; o.z = 0; o.w = 0;       // fully-masked group
  } else {
    const float4 f = reinterpret_cast<const float4*>(W1)[idx];
    o.x = f2bf(f.x); o.y = f2bf(f.y); o.z = f2bf(f.z); o.w = f2bf(f.w);
  }
  reinterpret_cast<ushort4*>(W1b)[idx] = o;
}

// Build V [4096,512] bf16
__global__ __launch_bounds__(256) void prep_v_kernel(const float* __restrict__ mu,
                                                     const float* __restrict__ log_var,
                                                     const float* __restrict__ eps0,
                                                     unsigned short* __restrict__ Vb) {
  int idx = blockIdx.x * 256 + threadIdx.x;
  int b = idx >> 9, j = idx & 511;
  float v;
  if (j == 0) {
    v = eps0[b] * expf(0.5f * log_var[(size_t)b * Ln]) + mu[(size_t)b * Ln];
  } else {
    v = mu[(size_t)b * Ln + j - 1];
  }
  Vb[idx] = f2bf(v);
}

// Fused: Hm = leaky_relu(V @ W1^T + b1); out = Hm @ W2^T + b2; sample.
// R6 structure (proven fastest: BK=64, MT=4, both operands global_load_lds,
// double-buffered, counted vmcnt(8)) with the per-m-tile epilogue
// de-serialized:
//  - separate 4KB S scratch -> no "done reading Bs" barrier
//  - loop-end barrier skipped on epilogue iters (S-barrier after lgkmcnt(0)
//    covers the buf-read vs next-STAGE-write hazard)
//  - eps + b1/W2/b2 preloaded BEFORE the prefetch STAGE (older than it) so
//    their use-waits are vmcnt(8), never draining the pipeline (R11 pattern)
//  - group-of-4 XCD striping (R12: FETCH 36MB + clean write-merge)
__global__ __launch_bounds__(256) void gemm_fused_kernel(
    const unsigned short* __restrict__ Vb,   // [4096,512] bf16
    const unsigned short* __restrict__ W1b,  // [16384,512] bf16
    const float* __restrict__ b1,            // [512,32]
    const float* __restrict__ W2,            // [512,2,32]
    const float* __restrict__ b2,            // [512,2]
    const float* __restrict__ eps,           // [4096,512]
    float* __restrict__ out)                 // [3, 4096, 512]
{
  const int tid  = threadIdx.x;
  const int wid  = tid >> 6;
  const int lane = tid & 63;
  const int l15  = lane & 15;
  const int lq   = lane >> 4;

  // ---- group-of-4 XCD striping: group g = bn>>2 lives on XCD g&7 (heavy first)
  const int bid  = blockIdx.x;
  const int xcd  = bid & 7;
  const int s    = bid >> 3;              // 0..127
  const int g    = xcd + 8 * (3 - (s >> 5));
  const int bn   = g * 4 + ((s >> 3) & 3);
  const int mg   = s & 7;
  const int mb   = mg * (MT * 128);
  const int nb   = bn * 128;

  // triangular cutoff: block's i in [bn*4, bn*4+3] -> j <= bn*4+3
  const int ksteps = min(8, (bn + 16) >> 4);  // ceil((4bn+4)/64)

  __shared__ unsigned short As[2 * 128 * 64];  // 2 x 16 KiB
  __shared__ unsigned short Bs[2 * 128 * 64];  // 2 x 16 KiB
  __shared__ float          Sx[1024];          // 4 KiB epilogue scratch

  // ---- staging: chunk = 8 rows x 128 B; lane -> (row=lane>>3, slot=lane&7).
  // LDS linear slot (row, s) receives global element (row, s ^ row) [16B slots].
  const int rowc = lane >> 3;
  const int sswz = (lane & 7) ^ rowc;
  const unsigned short* gA = Vb  + (size_t)(mb + wid * 32 + rowc) * Ln + sswz * 8;
  const unsigned short* gB = W1b + (size_t)(nb + wid * 32 + rowc) * Ln + sswz * 8;
  unsigned short* lA = As + wid * 2048;
  unsigned short* lB = Bs + wid * 2048;

  auto STAGE = [&](int bufw, int mt_, int k0e) {  // 8 VMEM ops per wave
    const int    lofs = bufw * 8192;
    const size_t ga   = (size_t)mt_ * (128 * Ln) + k0e;
#pragma unroll
    for (int j = 0; j < 4; ++j) {
      GLOAD_LDS16(gA + ga + (size_t)j * 8 * Ln, lA + lofs + j * 512);
      GLOAD_LDS16(gB + k0e + (size_t)j * 8 * Ln, lB + lofs + j * 512);
    }
  };

  // ---- fragment reads: row = base + l15 (+f*16); linear slot = (ks2*4+lq) ^ (row&7)
  const int arow = (wid >> 1) * 64 + l15;
  const int brow = (wid & 1) * 64 + l15;
  const int swz7 = l15 & 7;

  f32x4 acc[4][4];  // acc[fn][fm]: rows = n-side (i,h), cols = batch
#pragma unroll
  for (int fn = 0; fn < 4; ++fn)
#pragma unroll
    for (int fm = 0; fm < 4; ++fm) acc[fn][fm] = f32x4{0.f, 0.f, 0.f, 0.f};

  auto COMPUTE = [&](int bufc) {
    const int cofs = bufc * 8192;
#pragma unroll
    for (int ks2 = 0; ks2 < 2; ++ks2) {
      const int se = ((ks2 * 4 + lq) ^ swz7) * 8;
      bf16x8 a[4], b[4];
#pragma unroll
      for (int f = 0; f < 4; ++f) {
        a[f] = *reinterpret_cast<const bf16x8*>(As + cofs + (arow + f * 16) * 64 + se);
        b[f] = *reinterpret_cast<const bf16x8*>(Bs + cofs + (brow + f * 16) * 64 + se);
      }
#pragma unroll
      for (int fn = 0; fn < 4; ++fn)
#pragma unroll
        for (int fm = 0; fm < 4; ++fm)
          acc[fn][fm] = __builtin_amdgcn_mfma_f32_16x16x32_bf16(b[fn], a[fm],
                                                                acc[fn][fm], 0, 0, 0);
    }
  };

  float* mus = out;
  float* lvs = out + (size_t)Bn * Ln;
  float* smp = out + (size_t)2 * Bn * Ln;

  int buf = 0;
  STAGE(0, 0, 0);

  for (int mt = 0; mt < MT; ++mt) {
    for (int k = 0; k < ksteps; ++k) {
      int kn = k + 1, mtn = mt;
      if (kn == ksteps) { kn = 0; ++mtn; }
      const bool epi  = (k == ksteps - 1);
      const bool more = (mtn < MT);

      // ---- epilogue pre-window: 14 VMEM ops, ALL waves issue the same count
      // (eps row = tid&127 so waves 2,3 redundantly mirror 0,1 -> uniform
      // vmcnt bookkeeping). Issued BEFORE the prefetch so use-waits = vmcnt(8).
      float4 ep4;
      float4 b1q[2][2], w20q[2][2], w21q[2][2], b2q;
      if (epi) {
        int zero;  // address laundering: blocks LICM / SMEM promotion
        asm volatile("v_mov_b32 %0, 0" : "=v"(zero));
        const size_t eo = (size_t)(mb + mt * 128 + (tid & 127)) * Ln + bn * 4;
        ep4 = *reinterpret_cast<const float4*>(eps + eo + zero);      // 1
#pragma unroll
        for (int il = 0; il < 2; ++il) {
          const int i = bn * 4 + (wid & 1) * 2 + il;
#pragma unroll
          for (int q = 0; q < 2; ++q) {  // 12 x dwordx4
            const int hb = q * 16 + lq * 4 + zero;
            b1q[il][q]  = *reinterpret_cast<const float4*>(b1 + i * Hn + hb);
            w20q[il][q] = *reinterpret_cast<const float4*>(W2 + (i * 2 + 0) * Hn + hb);
            w21q[il][q] = *reinterpret_cast<const float4*>(W2 + (i * 2 + 1) * Hn + hb);
          }
        }
        // 1 x dwordx4: b2[i0*2 .. i0*2+3], i0 = bn*4+(wid&1)*2 (even -> aligned)
        b2q = *reinterpret_cast<const float4*>(b2 + (bn * 4 + (wid & 1) * 2) * 2 + zero);
        __builtin_amdgcn_sched_barrier(0);  // pin pre-window above STAGE
      }

      if (more) {
        STAGE(buf ^ 1, mtn, kn * 64);  // 8 newest
        if (epi) asm volatile("s_waitcnt vmcnt(22)" ::: "memory");  // drain cur8, keep 14+8
        else     asm volatile("s_waitcnt vmcnt(8)"  ::: "memory");  // drain cur8, keep 8
      } else {
        asm volatile("s_waitcnt vmcnt(14)" ::: "memory");           // drain cur8, keep 14
      }
      __builtin_amdgcn_s_barrier();
      __builtin_amdgcn_sched_barrier(0);  // pin ds_reads below the barrier
      COMPUTE(buf);

      if (epi) {
        // ======== per-m-tile epilogue: own scratch, ONE barrier total ========
        const int wrow = (wid >> 1) * 64;
#pragma unroll
        for (int il = 0; il < 2; ++il) {
          const int   icl   = (wid & 1) * 2 + il;
          const float bias0 = (il == 0) ? b2q.x : b2q.z;
          const float bias1 = (il == 0) ? b2q.y : b2q.w;
#pragma unroll
          for (int fm = 0; fm < 4; ++fm) {
            float p0 = 0.f, p1 = 0.f;
#pragma unroll
            for (int q = 0; q < 2; ++q) {
              const f32x4& A = acc[il * 2 + q][fm];
              const float* b1f = reinterpret_cast<const float*>(&b1q[il][q]);
              const float* w0f = reinterpret_cast<const float*>(&w20q[il][q]);
              const float* w1f = reinterpret_cast<const float*>(&w21q[il][q]);
#pragma unroll
              for (int r = 0; r < 4; ++r) {
                float x  = A[r] + b1f[r];
                float hv = fmaxf(x, 0.01f * x);  // leaky_relu (slope 0.01)
                p0 += hv * w0f[r];
                p1 += hv * w1f[r];
              }
            }
            p0 += __shfl_xor(p0, 16);
            p0 += __shfl_xor(p0, 32);
            p1 += __shfl_xor(p1, 16);
            p1 += __shfl_xor(p1, 32);
            if (lq == 0) {
              const int r = wrow + fm * 16 + l15;
              Sx[icl * 128 + r]       = p0 + bias0;
              Sx[512 + icl * 128 + r] = p1 + bias1;
            }
          }
        }
        // lgkmcnt(0) drains this wave's COMPUTE ds_reads AND its Sx writes;
        // the barrier then (a) makes Sx visible, (b) certifies all waves'
        // reads of Bs/As[buf] are done -> next STAGE may overwrite (this
        // replaces the loop-end barrier on epilogue iterations).
        asm volatile("s_waitcnt lgkmcnt(0)" ::: "memory");
        __builtin_amdgcn_s_barrier();

        if (tid < 128) {  // wave-uniform: waves 0,1 active
          const int    r = tid;
          const size_t o = (size_t)(mb + mt * 128 + r) * Ln + bn * 4;
          float4 muv, lvv;
          muv.x = Sx[r];       muv.y = Sx[128 + r]; muv.z = Sx[256 + r]; muv.w = Sx[384 + r];
          lvv.x = Sx[512 + r]; lvv.y = Sx[640 + r]; lvv.z = Sx[768 + r]; lvv.w = Sx[896 + r];
          float4 sm;
          sm.x = ep4.x * __builtin_exp2f(lvv.x * 0.7213475204444817f) + muv.x;
          sm.y = ep4.y * __builtin_exp2f(lvv.y * 0.7213475204444817f) + muv.y;
          sm.z = ep4.z * __builtin_exp2f(lvv.z * 0.7213475204444817f) + muv.z;
          sm.w = ep4.w * __builtin_exp2f(lvv.w * 0.7213475204444817f) + muv.w;
          *reinterpret_cast<float4*>(mus + o) = muv;
          *reinterpret_cast<float4*>(lvs + o) = lvv;
          *reinterpret_cast<float4*>(smp + o) = sm;
        }
        // reset accumulators for the next m-tile
#pragma unroll
        for (int fn = 0; fn < 4; ++fn)
#pragma unroll
          for (int fm = 0; fm < 4; ++fm) acc[fn][fm] = f32x4{0.f, 0.f, 0.f, 0.f};
      } else {
        __builtin_amdgcn_s_barrier();  // reads of buf done -> next STAGE may overwrite
      }
      buf ^= 1;
    }
  }
}

extern "C" void kernel_launch(void* const* d_in, const int* in_sizes, int n_in,
                              void* d_out, int out_size, void* d_ws, size_t ws_size,
                              hipStream_t stream) {
  const float* mu      = (const float*)d_in[0];
  const float* log_var = (const float*)d_in[1];
  const float* eps0    = (const float*)d_in[2];
  const float* eps     = (const float*)d_in[3];
  const float* W1      = (const float*)d_in[4];
  const float* b1      = (const float*)d_in[5];
  const float* W2      = (const float*)d_in[6];
  const float* b2      = (const float*)d_in[7];
  float* out = (float*)d_out;

  unsigned short* Vb  = (unsigned short*)d_ws;                                  // 4 MiB
  unsigned short* W1b = (unsigned short*)((char*)d_ws + (size_t)Bn * Ln * 2);   // 16 MiB

  prep_v_kernel<<<(Bn * Ln) / 256, 256, 0, stream>>>(mu, log_var, eps0, Vb);
  prep_w1_kernel<<<(Ln * Hn * Ln) / 4 / 256, 256, 0, stream>>>(W1, W1b);
  gemm_fused_kernel<<<128 * (32 / MT), 256, 0, stream>>>(
      Vb, W1b, b1, W2, b2, eps, out);
}

// Round 14
// 77.734 us; speedup vs baseline: 2.5153x; 1.0540x over previous
//
#include <hip/hip_runtime.h>
#include <hip/hip_bf16.h>

#define Bn 4096
#define Ln 512
#define Hn 32
#define MT 4  // m-tiles per block (grid = 128 bn x 8 mg)

using bf16x8 = __attribute__((ext_vector_type(8))) __bf16;
using f32x4  = __attribute__((ext_vector_type(4))) float;

#define GLOAD_LDS16(g, l)                                                          \
  __builtin_amdgcn_global_load_lds(                                                \
      (const __attribute__((address_space(1))) void*)(g),                          \
      (__attribute__((address_space(3))) void*)(l), 16, 0, 0)

__device__ __forceinline__ unsigned short f2bf(float x) {
  unsigned int u = __float_as_uint(x);
  unsigned int r = (u + 0x7FFFu + ((u >> 16) & 1u)) >> 16;
  return (unsigned short)r;
}

// Convert W1 [512*32*512] f32 -> bf16. Masked (upper-triangular) groups are
// ZERO-FILLED without reading W1. Reads ~half, writes all.
__global__ __launch_bounds__(256) void prep_w1_kernel(const float* __restrict__ W1,
                                                      unsigned short* __restrict__ W1b) {
  int idx = blockIdx.x * 256 + threadIdx.x;   // float4 group index
  const int n  = idx >> 7;                    // row in [0, 16384)
  const int c0 = (idx & 127) * 4;             // first col of group
  const int i  = n >> 5;                      // latent step of this row
  ushort4 o;
  if (c0 > i) {
    o.x = 0; o.y = 0; o.z = 0; o.w = 0;       // fully-masked group
  } else {
    const float4 f = reinterpret_cast<const float4*>(W1)[idx];
    o.x = f2bf(f.x); o.y = f2bf(f.y); o.z = f2bf(f.z); o.w = f2bf(f.w);
  }
  reinterpret_cast<ushort4*>(W1b)[idx] = o;
}

// Build V [4096,512] bf16
__global__ __launch_bounds__(256) void prep_v_kernel(const float* __restrict__ mu,
                                                     const float* __restrict__ log_var,
                                                     const float* __restrict__ eps0,
                                                     unsigned short* __restrict__ Vb) {
  int idx = blockIdx.x * 256 + threadIdx.x;
  int b = idx >> 9, j = idx & 511;
  float v;
  if (j == 0) {
    v = eps0[b] * expf(0.5f * log_var[(size_t)b * Ln]) + mu[(size_t)b * Ln];
  } else {
    v = mu[(size_t)b * Ln + j - 1];
  }
  Vb[idx] = f2bf(v);
}

// Fused: Hm = leaky_relu(V @ W1^T + b1); out = Hm @ W2^T + b2; sample.
// R13 champion + BALANCED XCD pairing. Group g (bn = 4g..4g+3) has
// ksteps = floor(g/4)+1; pairs (g, 31-g) sum to 9. XCD x gets groups
// {31-x, 23-x, 8+x, x} -> ksteps sum = 18 for EVERY XCD (old mapping gave
// XCD7 25% more K-iterations than XCD0; kernel time = max over XCDs).
// Group-of-4 integrity preserved (write-merge + W1-panel locality).
__global__ __launch_bounds__(256) void gemm_fused_kernel(
    const unsigned short* __restrict__ Vb,   // [4096,512] bf16
    const unsigned short* __restrict__ W1b,  // [16384,512] bf16
    const float* __restrict__ b1,            // [512,32]
    const float* __restrict__ W2,            // [512,2,32]
    const float* __restrict__ b2,            // [512,2]
    const float* __restrict__ eps,           // [4096,512]
    float* __restrict__ out)                 // [3, 4096, 512]
{
  const int tid  = threadIdx.x;
  const int wid  = tid >> 6;
  const int lane = tid & 63;
  const int l15  = lane & 15;
  const int lq   = lane >> 4;

  // ---- balanced group-of-4 XCD striping (heavy-first within each XCD)
  const int bid  = blockIdx.x;
  const int xcd  = bid & 7;
  const int s    = bid >> 3;              // 0..127
  const int sel  = s >> 5;                // 0..3, dispatch order = heavy first
  int g;
  switch (sel) {
    case 0:  g = 31 - xcd; break;  // ksteps 8..7
    case 1:  g = 23 - xcd; break;  // ksteps 6..5
    case 2:  g = 8 + xcd;  break;  // ksteps 3..4
    default: g = xcd;      break;  // ksteps 1..2
  }
  const int bn   = g * 4 + ((s >> 3) & 3);
  const int mg   = s & 7;
  const int mb   = mg * (MT * 128);
  const int nb   = bn * 128;

  // triangular cutoff: block's i in [bn*4, bn*4+3] -> j <= bn*4+3
  const int ksteps = min(8, (bn + 16) >> 4);  // ceil((4bn+4)/64)

  __shared__ unsigned short As[2 * 128 * 64];  // 2 x 16 KiB
  __shared__ unsigned short Bs[2 * 128 * 64];  // 2 x 16 KiB
  __shared__ float          Sx[1024];          // 4 KiB epilogue scratch

  // ---- staging: chunk = 8 rows x 128 B; lane -> (row=lane>>3, slot=lane&7).
  // LDS linear slot (row, s) receives global element (row, s ^ row) [16B slots].
  const int rowc = lane >> 3;
  const int sswz = (lane & 7) ^ rowc;
  const unsigned short* gA = Vb  + (size_t)(mb + wid * 32 + rowc) * Ln + sswz * 8;
  const unsigned short* gB = W1b + (size_t)(nb + wid * 32 + rowc) * Ln + sswz * 8;
  unsigned short* lA = As + wid * 2048;
  unsigned short* lB = Bs + wid * 2048;

  auto STAGE = [&](int bufw, int mt_, int k0e) {  // 8 VMEM ops per wave
    const int    lofs = bufw * 8192;
    const size_t ga   = (size_t)mt_ * (128 * Ln) + k0e;
#pragma unroll
    for (int j = 0; j < 4; ++j) {
      GLOAD_LDS16(gA + ga + (size_t)j * 8 * Ln, lA + lofs + j * 512);
      GLOAD_LDS16(gB + k0e + (size_t)j * 8 * Ln, lB + lofs + j * 512);
    }
  };

  // ---- fragment reads: row = base + l15 (+f*16); linear slot = (ks2*4+lq) ^ (row&7)
  const int arow = (wid >> 1) * 64 + l15;
  const int brow = (wid & 1) * 64 + l15;
  const int swz7 = l15 & 7;

  f32x4 acc[4][4];  // acc[fn][fm]: rows = n-side (i,h), cols = batch
#pragma unroll
  for (int fn = 0; fn < 4; ++fn)
#pragma unroll
    for (int fm = 0; fm < 4; ++fm) acc[fn][fm] = f32x4{0.f, 0.f, 0.f, 0.f};

  auto COMPUTE = [&](int bufc) {
    const int cofs = bufc * 8192;
#pragma unroll
    for (int ks2 = 0; ks2 < 2; ++ks2) {
      const int se = ((ks2 * 4 + lq) ^ swz7) * 8;
      bf16x8 a[4], b[4];
#pragma unroll
      for (int f = 0; f < 4; ++f) {
        a[f] = *reinterpret_cast<const bf16x8*>(As + cofs + (arow + f * 16) * 64 + se);
        b[f] = *reinterpret_cast<const bf16x8*>(Bs + cofs + (brow + f * 16) * 64 + se);
      }
#pragma unroll
      for (int fn = 0; fn < 4; ++fn)
#pragma unroll
        for (int fm = 0; fm < 4; ++fm)
          acc[fn][fm] = __builtin_amdgcn_mfma_f32_16x16x32_bf16(b[fn], a[fm],
                                                                acc[fn][fm], 0, 0, 0);
    }
  };

  float* mus = out;
  float* lvs = out + (size_t)Bn * Ln;
  float* smp = out + (size_t)2 * Bn * Ln;

  int buf = 0;
  STAGE(0, 0, 0);

  for (int mt = 0; mt < MT; ++mt) {
    for (int k = 0; k < ksteps; ++k) {
      int kn = k + 1, mtn = mt;
      if (kn == ksteps) { kn = 0; ++mtn; }
      const bool epi  = (k == ksteps - 1);
      const bool more = (mtn < MT);

      // ---- epilogue pre-window: 14 VMEM ops, ALL waves issue the same count
      // (eps row = tid&127 so waves 2,3 redundantly mirror 0,1 -> uniform
      // vmcnt bookkeeping). Issued BEFORE the prefetch so use-waits = vmcnt(8).
      float4 ep4;
      float4 b1q[2][2], w20q[2][2], w21q[2][2], b2q;
      if (epi) {
        int zero;  // address laundering: blocks LICM / SMEM promotion
        asm volatile("v_mov_b32 %0, 0" : "=v"(zero));
        const size_t eo = (size_t)(mb + mt * 128 + (tid & 127)) * Ln + bn * 4;
        ep4 = *reinterpret_cast<const float4*>(eps + eo + zero);      // 1
#pragma unroll
        for (int il = 0; il < 2; ++il) {
          const int i = bn * 4 + (wid & 1) * 2 + il;
#pragma unroll
          for (int q = 0; q < 2; ++q) {  // 12 x dwordx4
            const int hb = q * 16 + lq * 4 + zero;
            b1q[il][q]  = *reinterpret_cast<const float4*>(b1 + i * Hn + hb);
            w20q[il][q] = *reinterpret_cast<const float4*>(W2 + (i * 2 + 0) * Hn + hb);
            w21q[il][q] = *reinterpret_cast<const float4*>(W2 + (i * 2 + 1) * Hn + hb);
          }
        }
        // 1 x dwordx4: b2[i0*2 .. i0*2+3], i0 = bn*4+(wid&1)*2 (even -> aligned)
        b2q = *reinterpret_cast<const float4*>(b2 + (bn * 4 + (wid & 1) * 2) * 2 + zero);
        __builtin_amdgcn_sched_barrier(0);  // pin pre-window above STAGE
      }

      if (more) {
        STAGE(buf ^ 1, mtn, kn * 64);  // 8 newest
        if (epi) asm volatile("s_waitcnt vmcnt(22)" ::: "memory");  // drain cur8, keep 14+8
        else     asm volatile("s_waitcnt vmcnt(8)"  ::: "memory");  // drain cur8, keep 8
      } else {
        asm volatile("s_waitcnt vmcnt(14)" ::: "memory");           // drain cur8, keep 14
      }
      __builtin_amdgcn_s_barrier();
      __builtin_amdgcn_sched_barrier(0);  // pin ds_reads below the barrier
      COMPUTE(buf);

      if (epi) {
        // ======== per-m-tile epilogue: own scratch, ONE barrier total ========
        const int wrow = (wid >> 1) * 64;
#pragma unroll
        for (int il = 0; il < 2; ++il) {
          const int   icl   = (wid & 1) * 2 + il;
          const float bias0 = (il == 0) ? b2q.x : b2q.z;
          const float bias1 = (il == 0) ? b2q.y : b2q.w;
#pragma unroll
          for (int fm = 0; fm < 4; ++fm) {
            float p0 = 0.f, p1 = 0.f;
#pragma unroll
            for (int q = 0; q < 2; ++q) {
              const f32x4& A = acc[il * 2 + q][fm];
              const float* b1f = reinterpret_cast<const float*>(&b1q[il][q]);
              const float* w0f = reinterpret_cast<const float*>(&w20q[il][q]);
              const float* w1f = reinterpret_cast<const float*>(&w21q[il][q]);
#pragma unroll
              for (int r = 0; r < 4; ++r) {
                float x  = A[r] + b1f[r];
                float hv = fmaxf(x, 0.01f * x);  // leaky_relu (slope 0.01)
                p0 += hv * w0f[r];
                p1 += hv * w1f[r];
              }
            }
            p0 += __shfl_xor(p0, 16);
            p0 += __shfl_xor(p0, 32);
            p1 += __shfl_xor(p1, 16);
            p1 += __shfl_xor(p1, 32);
            if (lq == 0) {
              const int r = wrow + fm * 16 + l15;
              Sx[icl * 128 + r]       = p0 + bias0;
              Sx[512 + icl * 128 + r] = p1 + bias1;
            }
          }
        }
        // lgkmcnt(0) drains this wave's COMPUTE ds_reads AND its Sx writes;
        // the barrier then (a) makes Sx visible, (b) certifies all waves'
        // reads of Bs/As[buf] are done -> next STAGE may overwrite (this
        // replaces the loop-end barrier on epilogue iterations).
        asm volatile("s_waitcnt lgkmcnt(0)" ::: "memory");
        __builtin_amdgcn_s_barrier();

        if (tid < 128) {  // wave-uniform: waves 0,1 active
          const int    r = tid;
          const size_t o = (size_t)(mb + mt * 128 + r) * Ln + bn * 4;
          float4 muv, lvv;
          muv.x = Sx[r];       muv.y = Sx[128 + r]; muv.z = Sx[256 + r]; muv.w = Sx[384 + r];
          lvv.x = Sx[512 + r]; lvv.y = Sx[640 + r]; lvv.z = Sx[768 + r]; lvv.w = Sx[896 + r];
          float4 sm;
          sm.x = ep4.x * __builtin_exp2f(lvv.x * 0.7213475204444817f) + muv.x;
          sm.y = ep4.y * __builtin_exp2f(lvv.y * 0.7213475204444817f) + muv.y;
          sm.z = ep4.z * __builtin_exp2f(lvv.z * 0.7213475204444817f) + muv.z;
          sm.w = ep4.w * __builtin_exp2f(lvv.w * 0.7213475204444817f) + muv.w;
          *reinterpret_cast<float4*>(mus + o) = muv;
          *reinterpret_cast<float4*>(lvs + o) = lvv;
          *reinterpret_cast<float4*>(smp + o) = sm;
        }
        // reset accumulators for the next m-tile
#pragma unroll
        for (int fn = 0; fn < 4; ++fn)
#pragma unroll
          for (int fm = 0; fm < 4; ++fm) acc[fn][fm] = f32x4{0.f, 0.f, 0.f, 0.f};
      } else {
        __builtin_amdgcn_s_barrier();  // reads of buf done -> next STAGE may overwrite
      }
      buf ^= 1;
    }
  }
}

extern "C" void kernel_launch(void* const* d_in, const int* in_sizes, int n_in,
                              void* d_out, int out_size, void* d_ws, size_t ws_size,
                              hipStream_t stream) {
  const float* mu      = (const float*)d_in[0];
  const float* log_var = (const float*)d_in[1];
  const float* eps0    = (const float*)d_in[2];
  const float* eps     = (const float*)d_in[3];
  const float* W1      = (const float*)d_in[4];
  const float* b1      = (const float*)d_in[5];
  const float* W2      = (const float*)d_in[6];
  const float* b2      = (const float*)d_in[7];
  float* out = (float*)d_out;

  unsigned short* Vb  = (unsigned short*)d_ws;                                  // 4 MiB
  unsigned short* W1b = (unsigned short*)((char*)d_ws + (size_t)Bn * Ln * 2);   // 16 MiB

  prep_v_kernel<<<(Bn * Ln) / 256, 256, 0, stream>>>(mu, log_var, eps0, Vb);
  prep_w1_kernel<<<(Ln * Hn * Ln) / 4 / 256, 256, 0, stream>>>(W1, W1b);
  gemm_fused_kernel<<<128 * (32 / MT), 256, 0, stream>>>(
      Vb, W1b, b1, W2, b2, eps, out);
}

// Round 15
// 73.132 us; speedup vs baseline: 2.6736x; 1.0629x over previous
//
#include <hip/hip_runtime.h>
#include <hip/hip_bf16.h>

#define Bn 4096
#define Ln 512
#define Hn 32
#define MT 4  // m-tiles per block (grid = 128 bn x 8 mg)

using bf16x8 = __attribute__((ext_vector_type(8))) __bf16;
using f32x4  = __attribute__((ext_vector_type(4))) float;

#define GLOAD_LDS16(g, l)                                                          \
  __builtin_amdgcn_global_load_lds(                                                \
      (const __attribute__((address_space(1))) void*)(g),                          \
      (__attribute__((address_space(3))) void*)(l), 16, 0, 0)

__device__ __forceinline__ unsigned short f2bf(float x) {
  unsigned int u = __float_as_uint(x);
  unsigned int r = (u + 0x7FFFu + ((u >> 16) & 1u)) >> 16;
  return (unsigned short)r;
}

// Merged prep: blocks [0,8192) convert W1 f32->bf16 (zero-filling masked
// upper-triangular groups, reading only ~half); blocks [8192,16384) build V.
__global__ __launch_bounds__(256) void prep_kernel(
    const float* __restrict__ W1, unsigned short* __restrict__ W1b,
    const float* __restrict__ mu, const float* __restrict__ log_var,
    const float* __restrict__ eps0, unsigned short* __restrict__ Vb) {
  const int bid = blockIdx.x;
  if (bid < 8192) {
    int idx = bid * 256 + threadIdx.x;        // float4 group index
    const int n  = idx >> 7;                  // row in [0, 16384)
    const int c0 = (idx & 127) * 4;           // first col of group
    const int i  = n >> 5;                    // latent step of this row
    ushort4 o;
    if (c0 > i) {
      o.x = 0; o.y = 0; o.z = 0; o.w = 0;     // fully-masked group
    } else {
      const float4 f = reinterpret_cast<const float4*>(W1)[idx];
      o.x = f2bf(f.x); o.y = f2bf(f.y); o.z = f2bf(f.z); o.w = f2bf(f.w);
    }
    reinterpret_cast<ushort4*>(W1b)[idx] = o;
  } else {
    int idx = (bid - 8192) * 256 + threadIdx.x;  // B*L threads
    int b = idx >> 9, j = idx & 511;
    float v;
    if (j == 0) {
      v = eps0[b] * __builtin_exp2f(log_var[(size_t)b * Ln] * 0.7213475204444817f)
          + mu[(size_t)b * Ln];
    } else {
      v = mu[(size_t)b * Ln + j - 1];
    }
    Vb[idx] = f2bf(v);
  }
}

// Fused: Hm = leaky_relu(V @ W1^T + b1); out = Hm @ W2^T + b2; sample.
// R14 champion (BK=64, MT=4, both operands global_load_lds, double-buffered,
// counted vmcnt, balanced group-of-4 XCD pairing, barrier-free epilogue) +
//  - b1/W2/b2 hoisted to BLOCK START (block-constant across the 4 m-tiles;
//    VGPR is free at LDS-limited 2 blocks/CU) -> per-epilogue pre-window is
//    just 1 eps load; counted waits vmcnt(9)/vmcnt(1).
__global__ __launch_bounds__(256) void gemm_fused_kernel(
    const unsigned short* __restrict__ Vb,   // [4096,512] bf16
    const unsigned short* __restrict__ W1b,  // [16384,512] bf16
    const float* __restrict__ b1,            // [512,32]
    const float* __restrict__ W2,            // [512,2,32]
    const float* __restrict__ b2,            // [512,2]
    const float* __restrict__ eps,           // [4096,512]
    float* __restrict__ out)                 // [3, 4096, 512]
{
  const int tid  = threadIdx.x;
  const int wid  = tid >> 6;
  const int lane = tid & 63;
  const int l15  = lane & 15;
  const int lq   = lane >> 4;

  // ---- balanced group-of-4 XCD striping (heavy-first within each XCD).
  // Group g has ksteps = floor(g/4)+1; XCD x gets {31-x, 23-x, 8+x, x}
  // -> per-XCD ksteps sum = 18 exactly (R14: removed the 25% XCD7 tail).
  const int bid  = blockIdx.x;
  const int xcd  = bid & 7;
  const int s    = bid >> 3;              // 0..127
  const int sel  = s >> 5;                // 0..3, dispatch order = heavy first
  int g;
  switch (sel) {
    case 0:  g = 31 - xcd; break;
    case 1:  g = 23 - xcd; break;
    case 2:  g = 8 + xcd;  break;
    default: g = xcd;      break;
  }
  const int bn   = g * 4 + ((s >> 3) & 3);
  const int mg   = s & 7;
  const int mb   = mg * (MT * 128);
  const int nb   = bn * 128;

  // triangular cutoff: block's i in [bn*4, bn*4+3] -> j <= bn*4+3
  const int ksteps = min(8, (bn + 16) >> 4);  // ceil((4bn+4)/64)

  __shared__ unsigned short As[2 * 128 * 64];  // 2 x 16 KiB
  __shared__ unsigned short Bs[2 * 128 * 64];  // 2 x 16 KiB
  __shared__ float          Sx[1024];          // 4 KiB epilogue scratch

  // ---- staging: chunk = 8 rows x 128 B; lane -> (row=lane>>3, slot=lane&7).
  // LDS linear slot (row, s) receives global element (row, s ^ row) [16B slots].
  const int rowc = lane >> 3;
  const int sswz = (lane & 7) ^ rowc;
  const unsigned short* gA = Vb  + (size_t)(mb + wid * 32 + rowc) * Ln + sswz * 8;
  const unsigned short* gB = W1b + (size_t)(nb + wid * 32 + rowc) * Ln + sswz * 8;
  unsigned short* lA = As + wid * 2048;
  unsigned short* lB = Bs + wid * 2048;

  auto STAGE = [&](int bufw, int mt_, int k0e) {  // 8 VMEM ops per wave
    const int    lofs = bufw * 8192;
    const size_t ga   = (size_t)mt_ * (128 * Ln) + k0e;
#pragma unroll
    for (int j = 0; j < 4; ++j) {
      GLOAD_LDS16(gA + ga + (size_t)j * 8 * Ln, lA + lofs + j * 512);
      GLOAD_LDS16(gB + k0e + (size_t)j * 8 * Ln, lB + lofs + j * 512);
    }
  };

  // ---- hoisted epilogue constants (block-fixed; ~52 VGPR -- free at
  // LDS-limited 2 blocks/CU). Laundered address forces VMEM vector loads so
  // they stay in the vmcnt domain (oldest ops; drained by the first counted
  // wait, long since landed).
  int zero;
  asm volatile("v_mov_b32 %0, 0" : "=v"(zero));
  float4 b1q[2][2], w20q[2][2], w21q[2][2], b2q;
#pragma unroll
  for (int il = 0; il < 2; ++il) {
    const int i = bn * 4 + (wid & 1) * 2 + il;
#pragma unroll
    for (int q = 0; q < 2; ++q) {  // 12 x dwordx4
      const int hb = q * 16 + lq * 4 + zero;
      b1q[il][q]  = *reinterpret_cast<const float4*>(b1 + i * Hn + hb);
      w20q[il][q] = *reinterpret_cast<const float4*>(W2 + (i * 2 + 0) * Hn + hb);
      w21q[il][q] = *reinterpret_cast<const float4*>(W2 + (i * 2 + 1) * Hn + hb);
    }
  }
  b2q = *reinterpret_cast<const float4*>(b2 + (bn * 4 + (wid & 1) * 2) * 2 + zero);
  __builtin_amdgcn_sched_barrier(0);  // pin weight loads above the pipeline

  // ---- fragment reads: row = base + l15 (+f*16); linear slot = (ks2*4+lq) ^ (row&7)
  const int arow = (wid >> 1) * 64 + l15;
  const int brow = (wid & 1) * 64 + l15;
  const int swz7 = l15 & 7;

  f32x4 acc[4][4];  // acc[fn][fm]: rows = n-side (i,h), cols = batch
#pragma unroll
  for (int fn = 0; fn < 4; ++fn)
#pragma unroll
    for (int fm = 0; fm < 4; ++fm) acc[fn][fm] = f32x4{0.f, 0.f, 0.f, 0.f};

  auto COMPUTE = [&](int bufc) {
    const int cofs = bufc * 8192;
#pragma unroll
    for (int ks2 = 0; ks2 < 2; ++ks2) {
      const int se = ((ks2 * 4 + lq) ^ swz7) * 8;
      bf16x8 a[4], b[4];
#pragma unroll
      for (int f = 0; f < 4; ++f) {
        a[f] = *reinterpret_cast<const bf16x8*>(As + cofs + (arow + f * 16) * 64 + se);
        b[f] = *reinterpret_cast<const bf16x8*>(Bs + cofs + (brow + f * 16) * 64 + se);
      }
#pragma unroll
      for (int fn = 0; fn < 4; ++fn)
#pragma unroll
        for (int fm = 0; fm < 4; ++fm)
          acc[fn][fm] = __builtin_amdgcn_mfma_f32_16x16x32_bf16(b[fn], a[fm],
                                                                acc[fn][fm], 0, 0, 0);
    }
  };

  float* mus = out;
  float* lvs = out + (size_t)Bn * Ln;
  float* smp = out + (size_t)2 * Bn * Ln;

  int buf = 0;
  STAGE(0, 0, 0);

  for (int mt = 0; mt < MT; ++mt) {
    for (int k = 0; k < ksteps; ++k) {
      int kn = k + 1, mtn = mt;
      if (kn == ksteps) { kn = 0; ++mtn; }
      const bool epi  = (k == ksteps - 1);
      const bool more = (mtn < MT);

      // ---- epilogue pre-window: 1 eps load (all 256 lanes load tid&127's
      // row -> wave-uniform vmcnt counts), issued BEFORE the prefetch.
      float4 ep4;
      if (epi) {
        const size_t eo = (size_t)(mb + mt * 128 + (tid & 127)) * Ln + bn * 4;
        ep4 = *reinterpret_cast<const float4*>(eps + eo + zero);
        __builtin_amdgcn_sched_barrier(0);  // pin eps load above STAGE
      }

      if (more) {
        STAGE(buf ^ 1, mtn, kn * 64);  // 8 newest
        if (epi) asm volatile("s_waitcnt vmcnt(9)" ::: "memory");  // keep eps+8
        else     asm volatile("s_waitcnt vmcnt(8)" ::: "memory");  // keep 8
      } else {
        asm volatile("s_waitcnt vmcnt(1)" ::: "memory");           // keep eps
      }
      __builtin_amdgcn_s_barrier();
      __builtin_amdgcn_sched_barrier(0);  // pin ds_reads below the barrier
      COMPUTE(buf);

      if (epi) {
        // ======== per-m-tile epilogue: own scratch, ONE barrier total ========
        const int wrow = (wid >> 1) * 64;
#pragma unroll
        for (int il = 0; il < 2; ++il) {
          const int   icl   = (wid & 1) * 2 + il;
          const float bias0 = (il == 0) ? b2q.x : b2q.z;
          const float bias1 = (il == 0) ? b2q.y : b2q.w;
#pragma unroll
          for (int fm = 0; fm < 4; ++fm) {
            float p0 = 0.f, p1 = 0.f;
#pragma unroll
            for (int q = 0; q < 2; ++q) {
              const f32x4& A = acc[il * 2 + q][fm];
              const float* b1f = reinterpret_cast<const float*>(&b1q[il][q]);
              const float* w0f = reinterpret_cast<const float*>(&w20q[il][q]);
              const float* w1f = reinterpret_cast<const float*>(&w21q[il][q]);
#pragma unroll
              for (int r = 0; r < 4; ++r) {
                float x  = A[r] + b1f[r];
                float hv = fmaxf(x, 0.01f * x);  // leaky_relu (slope 0.01)
                p0 += hv * w0f[r];
                p1 += hv * w1f[r];
              }
            }
            p0 += __shfl_xor(p0, 16);
            p0 += __shfl_xor(p0, 32);
            p1 += __shfl_xor(p1, 16);
            p1 += __shfl_xor(p1, 32);
            if (lq == 0) {
              const int r = wrow + fm * 16 + l15;
              Sx[icl * 128 + r]       = p0 + bias0;
              Sx[512 + icl * 128 + r] = p1 + bias1;
            }
          }
        }
        // lgkmcnt(0) drains this wave's COMPUTE ds_reads AND its Sx writes;
        // the barrier then (a) makes Sx visible, (b) certifies all waves'
        // reads of As/Bs[buf] are done -> next STAGE may overwrite (this
        // replaces the loop-end barrier on epilogue iterations).
        asm volatile("s_waitcnt lgkmcnt(0)" ::: "memory");
        __builtin_amdgcn_s_barrier();

        if (tid < 128) {  // wave-uniform: waves 0,1 active
          const int    r = tid;
          const size_t o = (size_t)(mb + mt * 128 + r) * Ln + bn * 4;
          float4 muv, lvv;
          muv.x = Sx[r];       muv.y = Sx[128 + r]; muv.z = Sx[256 + r]; muv.w = Sx[384 + r];
          lvv.x = Sx[512 + r]; lvv.y = Sx[640 + r]; lvv.z = Sx[768 + r]; lvv.w = Sx[896 + r];
          float4 sm;
          sm.x = ep4.x * __builtin_exp2f(lvv.x * 0.7213475204444817f) + muv.x;
          sm.y = ep4.y * __builtin_exp2f(lvv.y * 0.7213475204444817f) + muv.y;
          sm.z = ep4.z * __builtin_exp2f(lvv.z * 0.7213475204444817f) + muv.z;
          sm.w = ep4.w * __builtin_exp2f(lvv.w * 0.7213475204444817f) + muv.w;
          *reinterpret_cast<float4*>(mus + o) = muv;
          *reinterpret_cast<float4*>(lvs + o) = lvv;
          *reinterpret_cast<float4*>(smp + o) = sm;
        }
        // reset accumulators for the next m-tile
#pragma unroll
        for (int fn = 0; fn < 4; ++fn)
#pragma unroll
          for (int fm = 0; fm < 4; ++fm) acc[fn][fm] = f32x4{0.f, 0.f, 0.f, 0.f};
      } else {
        __builtin_amdgcn_s_barrier();  // reads of buf done -> next STAGE may overwrite
      }
      buf ^= 1;
    }
  }
}

extern "C" void kernel_launch(void* const* d_in, const int* in_sizes, int n_in,
                              void* d_out, int out_size, void* d_ws, size_t ws_size,
                              hipStream_t stream) {
  const float* mu      = (const float*)d_in[0];
  const float* log_var = (const float*)d_in[1];
  const float* eps0    = (const float*)d_in[2];
  const float* eps     = (const float*)d_in[3];
  const float* W1      = (const float*)d_in[4];
  const float* b1      = (const float*)d_in[5];
  const float* W2      = (const float*)d_in[6];
  const float* b2      = (const float*)d_in[7];
  float* out = (float*)d_out;

  unsigned short* Vb  = (unsigned short*)d_ws;                                  // 4 MiB
  unsigned short* W1b = (unsigned short*)((char*)d_ws + (size_t)Bn * Ln * 2);   // 16 MiB

  prep_kernel<<<16384, 256, 0, stream>>>(W1, W1b, mu, log_var, eps0, Vb);
  gemm_fused_kernel<<<128 * (32 / MT), 256, 0, stream>>>(
      Vb, W1b, b1, W2, b2, eps, out);
}